// Round 2
// baseline (427.460 us; speedup 1.0000x reference)
//
#include <hip/hip_runtime.h>
#include <math.h>

#define NOBJ 8
#define NP   65536
#define NM   32
#define ND   128
#define CHUNKS 64            // chunks per object -> 512 blocks total
#define PTS_WG 1024          // points per block (8 waves * 128)
#define PTS_WAVE 128         // points per wave

// One block = 1024 points of one object, 512 threads (8 waves).
// LDS: nibble subset-sum tables T[8][16][128] fp32 (64KB) + esq + packed words.
// ~68.5KB LDS -> 2 blocks/CU -> 16 waves/CU (4/SIMD).
// Waves destagger after the single table barrier: Wlds is wave-private, so no
// block barrier between phase 1 (mask pack) and phase 2 (x stream) — phases
// overlap across waves (mask HBM || x HBM || LDS table reads).
__launch_bounds__(512, 4)
__global__ void distill_main(const float* __restrict__ net,
                             const float* __restrict__ embs,
                             const int* __restrict__ mask,
                             float* __restrict__ ws) {
  __shared__ float T[8 * 16 * ND];      // T[g][n][d] = sum of e rows in nibble n of group g
  __shared__ float esq[NM];             // ||e_m||^2 (nan-cleaned)
  __shared__ int   Wlds[PTS_WG];        // packed 32-bit mask word per point (wave-private slices)
  __shared__ float red[8][4];

  const int tid  = threadIdx.x;
  const int wave = tid >> 6;            // 0..7
  const int lane = tid & 63;
  const int o     = blockIdx.x >> 6;
  const int chunk = blockIdx.x & (CHUNKS - 1);

  const float* EB = embs + (size_t)o * NM * ND;

  // ---- pre-issue first mask batch: HBM latency hides under table build ----
  const int p0 = chunk * PTS_WG + wave * PTS_WAVE;
  const int* mp = mask + (size_t)o * NM * NP + p0 + 2 * lane;
  int2 v[8], u[8];
#pragma unroll
  for (int j = 0; j < 8; ++j) v[j] = *(const int2*)(mp + (size_t)j * NP);

  // ---- esq[m] = sum_d clean(e)^2 (wave 0 only; overlaps others' build) ----
  if (tid < NM) {
    float a = 0.f;
    const float* e = EB + (size_t)tid * ND;
    for (int d_ = 0; d_ < ND; ++d_) {
      float x = e[d_];
      if (!isfinite(x)) x = 0.f;
      a += x * x;
    }
    esq[tid] = a;
  }

  // ---- build nibble subset-sum tables: 2 (g,d) pairs per thread,
  //      4 e-loads each, all 16 subset sums in registers ----
#pragma unroll
  for (int k = 0; k < 2; ++k) {
    const int q  = tid + k * 512;       // (g,d) pair index, 0..1023
    const int d_ = q & (ND - 1);
    const int g  = q >> 7;
    float e0 = EB[(size_t)(g * 4 + 0) * ND + d_];
    float e1 = EB[(size_t)(g * 4 + 1) * ND + d_];
    float e2 = EB[(size_t)(g * 4 + 2) * ND + d_];
    float e3 = EB[(size_t)(g * 4 + 3) * ND + d_];
    if (!isfinite(e0)) e0 = 0.f;
    if (!isfinite(e1)) e1 = 0.f;
    if (!isfinite(e2)) e2 = 0.f;
    if (!isfinite(e3)) e3 = 0.f;
    const float a01[4] = {0.f, e0, e1, e0 + e1};
    const float a23[4] = {0.f, e2, e3, e2 + e3};
    float* Tg = &T[(size_t)(g * 16) * ND + d_];
#pragma unroll
    for (int n = 0; n < 16; ++n)
      Tg[(size_t)n * ND] = a01[n & 3] + a23[n >> 2];
  }
  __syncthreads();                      // the only pre-stream block barrier (T + esq ready)

  // ---- pre-issue iter-0 x loads: start the x stream before mask packing ----
  const float* xo = net + ((size_t)o * NP + p0) * ND;
  const int half = lane >> 5;           // which point of each pair
  const int dl   = (lane & 31) * 4;     // 4 dims per lane
  float4 Xa0 = *(const float4*)(xo + (size_t)(0 + half) * ND + dl);
  float4 Xa1 = *(const float4*)(xo + (size_t)(2 + half) * ND + dl);
  float4 Xb0 = *(const float4*)(xo + (size_t)(4 + half) * ND + dl);
  float4 Xb1 = *(const float4*)(xo + (size_t)(6 + half) * ND + dl);

  // ---- phase 1: pack mask bits, accumulate cnt terms (8-deep load batches) ----
  int W0 = 0, W1 = 0;
  float pB = 0.f, TPl = 0.f;
#pragma unroll
  for (int b = 0; b < 4; ++b) {
    if (b < 3) {
#pragma unroll
      for (int j = 0; j < 8; ++j)
        u[j] = *(const int2*)(mp + (size_t)((b + 1) * 8 + j) * NP);
    }
#pragma unroll
    for (int j = 0; j < 8; ++j) {
      const int m = b * 8 + j;
      int b0 = (v[j].x != 0), b1 = (v[j].y != 0);
      W0 |= b0 << m; W1 |= b1 << m;
      float c = (float)(b0 + b1);
      TPl += c;
      pB  += esq[m] * c;
    }
    if (b < 3) {
#pragma unroll
      for (int j = 0; j < 8; ++j) v[j] = u[j];
    }
  }
  *(int2*)&Wlds[wave * PTS_WAVE + 2 * lane] = make_int2(W0, W1);
  // Wlds slice is wave-private; DS is in-order per wave -> no block barrier.
  asm volatile("s_waitcnt lgkmcnt(0)" ::: "memory");

  // ---- phase 2: stream x, 8 points/iter, prefetch next 8 (4KB in flight/wave) ----
  const int base = wave * PTS_WAVE;
  float accA = 0.f, accC = 0.f;

  auto comp = [&](const float4 X, const int W) {
    accA += (float)__popc(W) * (X.x * X.x + X.y * X.y + X.z * X.z + X.w * X.w);
    float s0 = 0.f, s1 = 0.f, s2 = 0.f, s3 = 0.f;
#pragma unroll
    for (int g = 0; g < 8; ++g) {
      int n = (W >> (g * 4)) & 15;
      const float4 t = *(const float4*)&T[(g * 16 + n) * ND + dl];
      s0 += t.x; s1 += t.y; s2 += t.z; s3 += t.w;
    }
    accC += s0 * X.x + s1 * X.y + s2 * X.z + s3 * X.w;
  };

  int Wq0 = Wlds[base + 0 + half], Wq1 = Wlds[base + 2 + half];
  int Wq2 = Wlds[base + 4 + half], Wq3 = Wlds[base + 6 + half];

  for (int i = 0; i < PTS_WAVE; i += 8) {
    int pf = i + 8;
    pf = (pf < PTS_WAVE) ? pf : 0;      // last prefetch wraps; values unused
    float4 Ta0 = *(const float4*)(xo + (size_t)(pf + 0 + half) * ND + dl);
    float4 Ta1 = *(const float4*)(xo + (size_t)(pf + 2 + half) * ND + dl);
    float4 Tb0 = *(const float4*)(xo + (size_t)(pf + 4 + half) * ND + dl);
    float4 Tb1 = *(const float4*)(xo + (size_t)(pf + 6 + half) * ND + dl);
    int Tw0 = Wlds[base + pf + 0 + half], Tw1 = Wlds[base + pf + 2 + half];
    int Tw2 = Wlds[base + pf + 4 + half], Tw3 = Wlds[base + pf + 6 + half];

    comp(Xa0, Wq0);
    comp(Xa1, Wq1);
    comp(Xb0, Wq2);
    comp(Xb1, Wq3);

    Xa0 = Ta0; Xa1 = Ta1; Xb0 = Tb0; Xb1 = Tb1;
    Wq0 = Tw0; Wq1 = Tw1; Wq2 = Tw2; Wq3 = Tw3;
  }

  // ---- reduce: wave shfl-xor -> LDS -> block -> global atomics ----
#pragma unroll
  for (int off = 32; off >= 1; off >>= 1) {
    accA += __shfl_xor(accA, off, 64);
    accC += __shfl_xor(accC, off, 64);
    pB   += __shfl_xor(pB,   off, 64);
    TPl  += __shfl_xor(TPl,  off, 64);
  }
  if (lane == 0) {
    red[wave][0] = accA; red[wave][1] = pB;
    red[wave][2] = accC; red[wave][3] = TPl;
  }
  __syncthreads();
  if (tid == 0) {
    float A = 0.f, B = 0.f, C = 0.f, TP = 0.f;
    for (int w = 0; w < 8; ++w) {
      A += red[w][0]; B += red[w][1]; C += red[w][2]; TP += red[w][3];
    }
    atomicAdd(&ws[0], A);
    atomicAdd(&ws[1], B);
    atomicAdd(&ws[2], C);
    atomicAdd(&ws[3], TP);
  }
}

__global__ void distill_final(const float* __restrict__ ws, float* __restrict__ out) {
  float A = ws[0], B = ws[1], C = ws[2], TP = ws[3];
  out[0] = (TP > 0.f) ? (A + B - 2.f * C) / ((float)ND * TP) : 0.f;
}

extern "C" void kernel_launch(void* const* d_in, const int* in_sizes, int n_in,
                              void* d_out, int out_size, void* d_ws, size_t ws_size,
                              hipStream_t stream) {
  const float* net  = (const float*)d_in[0];
  const float* embs = (const float*)d_in[2];
  const int*   mask = (const int*)d_in[3];
  float* ws = (float*)d_ws;

  hipMemsetAsync(d_ws, 0, 4 * sizeof(float), stream);
  distill_main<<<NOBJ * CHUNKS, 512, 0, stream>>>(net, embs, mask, ws);
  distill_final<<<1, 1, 0, stream>>>(ws, (float*)d_out);
}

// Round 3
// 421.983 us; speedup vs baseline: 1.0130x; 1.0130x over previous
//
#include <hip/hip_runtime.h>
#include <hip/hip_fp16.h>
#include <math.h>

#define NOBJ 8
#define NP   65536
#define NM   32
#define ND   128
#define CHUNKS 64            // chunks per object -> 512 blocks total
#define PTS_WG 1024          // points per block (8 waves * 128)
#define PTS_WAVE 128         // points per wave

// One block = 1024 points of one object, 512 threads (8 waves).
// LDS: nibble subset-sum tables packed fp16: Tp[8][16][64] uint32 (32KB).
// fp16 is numerically safe here: loss divides by 128*TP ~ 1.07e9, so table
// rounding (rel ~5e-4, random sign, averaged over ~5e8 terms) perturbs the
// output by ~1e-8 absolute.
// ~36.6KB LDS -> 2 blocks/CU (VGPR-limited) -> 16 waves/CU.
// Waves destagger after the single table barrier: Wlds is wave-private.
__launch_bounds__(512, 4)
__global__ void distill_main(const float* __restrict__ net,
                             const float* __restrict__ embs,
                             const int* __restrict__ mask,
                             float* __restrict__ ws) {
  __shared__ unsigned Tp[8 * 16 * 64];  // Tp[g][n][d2] = half2(sum dims 2d2, 2d2+1)
  __shared__ float esq[NM];             // ||e_m||^2 (nan-cleaned)
  __shared__ int   Wlds[PTS_WG];        // packed 32-bit mask word per point (wave-private slices)
  __shared__ float red[8][4];

  const int tid  = threadIdx.x;
  const int wave = tid >> 6;            // 0..7
  const int lane = tid & 63;
  const int o     = blockIdx.x >> 6;
  const int chunk = blockIdx.x & (CHUNKS - 1);

  const float* EB = embs + (size_t)o * NM * ND;

  // ---- pre-issue first mask batch: HBM latency hides under table build ----
  const int p0 = chunk * PTS_WG + wave * PTS_WAVE;
  const int* mp = mask + (size_t)o * NM * NP + p0 + 2 * lane;
  int2 v[8], u[8];
#pragma unroll
  for (int j = 0; j < 8; ++j) v[j] = *(const int2*)(mp + (size_t)j * NP);

  // ---- esq[m] = sum_d clean(e)^2 (one wave; overlaps others' build) ----
  if (tid < NM) {
    float a = 0.f;
    const float* e = EB + (size_t)tid * ND;
    for (int d_ = 0; d_ < ND; ++d_) {
      float x = e[d_];
      if (!isfinite(x)) x = 0.f;
      a += x * x;
    }
    esq[tid] = a;
  }

  // ---- build packed-fp16 nibble subset-sum tables: one (g,d2) pair/thread ----
  {
    const int d2 = tid & 63;            // uint index: dims 2*d2, 2*d2+1
    const int g  = tid >> 6;            // 0..7
    float lo[4], hi[4];
#pragma unroll
    for (int b = 0; b < 4; ++b) {
      float2 e = *(const float2*)&EB[(size_t)(g * 4 + b) * ND + 2 * d2];
      lo[b] = isfinite(e.x) ? e.x : 0.f;
      hi[b] = isfinite(e.y) ? e.y : 0.f;
    }
    const float a01l[4] = {0.f, lo[0], lo[1], lo[0] + lo[1]};
    const float a23l[4] = {0.f, lo[2], lo[3], lo[2] + lo[3]};
    const float a01h[4] = {0.f, hi[0], hi[1], hi[0] + hi[1]};
    const float a23h[4] = {0.f, hi[2], hi[3], hi[2] + hi[3]};
    unsigned* Tg = &Tp[(size_t)(g * 16) * 64 + d2];
#pragma unroll
    for (int n = 0; n < 16; ++n) {
      __half2 h = __floats2half2_rn(a01l[n & 3] + a23l[n >> 2],
                                    a01h[n & 3] + a23h[n >> 2]);
      Tg[(size_t)n * 64] = *reinterpret_cast<unsigned*>(&h);
    }
  }
  __syncthreads();                      // the only pre-stream block barrier (Tp + esq ready)

  // ---- pre-issue iter-0 x loads: start the x stream before mask packing ----
  const float* xo = net + ((size_t)o * NP + p0) * ND;
  const int half = lane >> 5;           // which point of each pair
  const int dl   = (lane & 31) * 4;     // 4 dims per lane (fp32 X)
  const int dl2  = (lane & 31) * 2;     // 2 uints per lane (packed table)
  float4 Xa0 = *(const float4*)(xo + (size_t)(0 + half) * ND + dl);
  float4 Xa1 = *(const float4*)(xo + (size_t)(2 + half) * ND + dl);
  float4 Xb0 = *(const float4*)(xo + (size_t)(4 + half) * ND + dl);
  float4 Xb1 = *(const float4*)(xo + (size_t)(6 + half) * ND + dl);

  // ---- phase 1: pack mask bits, accumulate cnt terms (8-deep load batches) ----
  int W0 = 0, W1 = 0;
  float pB = 0.f, TPl = 0.f;
#pragma unroll
  for (int b = 0; b < 4; ++b) {
    if (b < 3) {
#pragma unroll
      for (int j = 0; j < 8; ++j)
        u[j] = *(const int2*)(mp + (size_t)((b + 1) * 8 + j) * NP);
    }
#pragma unroll
    for (int j = 0; j < 8; ++j) {
      const int m = b * 8 + j;
      int b0 = (v[j].x != 0), b1 = (v[j].y != 0);
      W0 |= b0 << m; W1 |= b1 << m;
      float c = (float)(b0 + b1);
      TPl += c;
      pB  += esq[m] * c;
    }
    if (b < 3) {
#pragma unroll
      for (int j = 0; j < 8; ++j) v[j] = u[j];
    }
  }
  *(int2*)&Wlds[wave * PTS_WAVE + 2 * lane] = make_int2(W0, W1);
  // Wlds slice is wave-private; DS is in-order per wave -> no block barrier.
  asm volatile("s_waitcnt lgkmcnt(0)" ::: "memory");

  // ---- phase 2: stream x, 8 points/iter, prefetch next 8 (4KB in flight/wave) ----
  const int base = wave * PTS_WAVE;
  float accA = 0.f, accC = 0.f;

  auto comp = [&](const float4 X, const int W) {
    accA += (float)__popc(W) * (X.x * X.x + X.y * X.y + X.z * X.z + X.w * X.w);
    __half2 s01 = __float2half2_rn(0.f);
    __half2 s23 = __float2half2_rn(0.f);
#pragma unroll
    for (int g = 0; g < 8; ++g) {
      int n = (W >> (g * 4)) & 15;
      uint2 t = *(const uint2*)&Tp[(size_t)(g * 16 + n) * 64 + dl2];
      unsigned tx = t.x, ty = t.y;
      s01 = __hadd2(s01, *reinterpret_cast<__half2*>(&tx));
      s23 = __hadd2(s23, *reinterpret_cast<__half2*>(&ty));
    }
    accC += __low2float(s01)  * X.x + __high2float(s01) * X.y
          + __low2float(s23)  * X.z + __high2float(s23) * X.w;
  };

  int Wq0 = Wlds[base + 0 + half], Wq1 = Wlds[base + 2 + half];
  int Wq2 = Wlds[base + 4 + half], Wq3 = Wlds[base + 6 + half];

  for (int i = 0; i < PTS_WAVE; i += 8) {
    int pf = i + 8;
    pf = (pf < PTS_WAVE) ? pf : 0;      // last prefetch wraps; values unused
    float4 Ta0 = *(const float4*)(xo + (size_t)(pf + 0 + half) * ND + dl);
    float4 Ta1 = *(const float4*)(xo + (size_t)(pf + 2 + half) * ND + dl);
    float4 Tb0 = *(const float4*)(xo + (size_t)(pf + 4 + half) * ND + dl);
    float4 Tb1 = *(const float4*)(xo + (size_t)(pf + 6 + half) * ND + dl);
    int Tw0 = Wlds[base + pf + 0 + half], Tw1 = Wlds[base + pf + 2 + half];
    int Tw2 = Wlds[base + pf + 4 + half], Tw3 = Wlds[base + pf + 6 + half];

    comp(Xa0, Wq0);
    comp(Xa1, Wq1);
    comp(Xb0, Wq2);
    comp(Xb1, Wq3);

    Xa0 = Ta0; Xa1 = Ta1; Xb0 = Tb0; Xb1 = Tb1;
    Wq0 = Tw0; Wq1 = Tw1; Wq2 = Tw2; Wq3 = Tw3;
  }

  // ---- reduce: wave shfl-xor -> LDS -> block -> global atomics ----
#pragma unroll
  for (int off = 32; off >= 1; off >>= 1) {
    accA += __shfl_xor(accA, off, 64);
    accC += __shfl_xor(accC, off, 64);
    pB   += __shfl_xor(pB,   off, 64);
    TPl  += __shfl_xor(TPl,  off, 64);
  }
  if (lane == 0) {
    red[wave][0] = accA; red[wave][1] = pB;
    red[wave][2] = accC; red[wave][3] = TPl;
  }
  __syncthreads();
  if (tid == 0) {
    float A = 0.f, B = 0.f, C = 0.f, TP = 0.f;
    for (int w = 0; w < 8; ++w) {
      A += red[w][0]; B += red[w][1]; C += red[w][2]; TP += red[w][3];
    }
    atomicAdd(&ws[0], A);
    atomicAdd(&ws[1], B);
    atomicAdd(&ws[2], C);
    atomicAdd(&ws[3], TP);
  }
}

__global__ void distill_final(const float* __restrict__ ws, float* __restrict__ out) {
  float A = ws[0], B = ws[1], C = ws[2], TP = ws[3];
  out[0] = (TP > 0.f) ? (A + B - 2.f * C) / ((float)ND * TP) : 0.f;
}

extern "C" void kernel_launch(void* const* d_in, const int* in_sizes, int n_in,
                              void* d_out, int out_size, void* d_ws, size_t ws_size,
                              hipStream_t stream) {
  const float* net  = (const float*)d_in[0];
  const float* embs = (const float*)d_in[2];
  const int*   mask = (const int*)d_in[3];
  float* ws = (float*)d_ws;

  hipMemsetAsync(d_ws, 0, 4 * sizeof(float), stream);
  distill_main<<<NOBJ * CHUNKS, 512, 0, stream>>>(net, embs, mask, ws);
  distill_final<<<1, 1, 0, stream>>>(ws, (float*)d_out);
}